// Round 8
// baseline (650.888 us; speedup 1.0000x reference)
//
#include <hip/hip_runtime.h>
#include <hip/hip_bf16.h>

typedef __bf16 bf16x8 __attribute__((ext_vector_type(8)));
typedef __bf16 bf16x4 __attribute__((ext_vector_type(4)));
typedef float  f32x16 __attribute__((ext_vector_type(16)));

#define MFMA __builtin_amdgcn_mfma_f32_32x32x16_bf16
#define BM 32            // batch rows per block (1 batch-tile) -> 4 blocks/CU
#define S  520           // bf16 elems per LDS activation row (512 + 8)
#define SF 260           // f32 elems per LDS row for out staging (same 1040 B)

// ---------------- weight prepack (identical to round-0, verified) ----------
// A-operand = W^T for v_mfma_f32_32x32x16_bf16.
// A[m][k]: m = lane&31 (out-feature), k = (lane>>5)*8 + j.
// Packed unit u = unitBase[w] + ((mt*Kc + kc)*64 + lane), Kc = K/16; 8 bf16:
//   elem j = W[kc*16 + (lane>>5)*8 + j][mt*32 + (lane&31)]
struct PrepParams {
    const float* src[9];
    int Kt[9];       // K/32
    int Mg[9];       // N/128 (col groups)
    int N[9];
    int blkEnd[9];
    int unitBase[9];
};

__global__ void __launch_bounds__(256)
prep_weights(PrepParams p, uint4* __restrict__ dst) {
    __shared__ float tile[32][128];
    int b = blockIdx.x;
    int w = 0;
    while (b >= p.blkEnd[w]) ++w;
    int local = b - ((w == 0) ? 0 : p.blkEnd[w - 1]);
    int mgc = p.Mg[w];
    int kt = local / mgc;
    int mg = local - kt * mgc;
    const float* src = p.src[w];
    int N = p.N[w];
    int Kc = p.Kt[w] * 2;
    int t = threadIdx.x;

    int row0 = kt * 32, col0 = mg * 128;
#pragma unroll
    for (int i = 0; i < 4; ++i) {
        int e4 = t + i * 256;            // 1024 float4 in 32x128 tile
        int r = e4 >> 5;
        int c4 = e4 & 31;
        float4 v = *(const float4*)&src[(size_t)(row0 + r) * N + col0 + c4 * 4];
        *(float4*)&tile[r][c4 * 4] = v;
    }
    __syncthreads();

#pragma unroll
    for (int rep = 0; rep < 2; ++rep) {
        int ul = t + rep * 256;          // 512 units per block
        int lane = ul & 63;
        int kcl = (ul >> 6) & 1;
        int mtl = ul >> 7;               // 0..3
        int gUnit = p.unitBase[w] +
                    ((mg * 4 + mtl) * Kc + (kt * 2 + kcl)) * 64 + lane;
        int lr = kcl * 16 + ((lane >> 5) << 3);
        int lc = mtl * 32 + (lane & 31);
        alignas(16) unsigned short u8[8];
#pragma unroll
        for (int j = 0; j < 8; ++j)
            u8[j] = __builtin_bit_cast(unsigned short, (__bf16)tile[lr + j][lc]);
        dst[gUnit] = *(const uint4*)u8;
    }
}

// ---------------- fused MLP ----------------
struct MlpParams {
    const float* X[3];
    const unsigned short* Wp[3];
    const float* B1[3];
    const float* B2[3];
    const float* B3[3];
    int dIn[3];
    int Nt[3];
    int rowOff[3];
};

__device__ __forceinline__ float sigmoidf(float z) {
    return __builtin_amdgcn_rcpf(
        1.0f + __builtin_amdgcn_exp2f(-1.442695040888963f * z));
}

// BM=32 layer: 4 waves, wave = 1 batch-tile x MT mtiles. Each wave reads B
// ONCE per k (redundancy 8->4 vs r7: LDS B-traffic per unit work halved).
// A streams global->reg, depth-2 ring, static indices (spill-free budget:
// acc MT*16 <= 64 AGPR + ring 2*MT*4 <= 32 + b 4 + addr ~20 <= 128-class).
// Early sigmoid (r7-proven): bias+sigmoid on acc pre-barrier; pack+write post.
template <int K16, int MT, bool TO_LDS>
__device__ __forceinline__ void layerP(
    unsigned short* __restrict__ buf,
    const unsigned short* __restrict__ W,
    const float* __restrict__ bias,
    int wave, int lane)
{
    const int half = lane >> 5;
    const int lr = lane & 31;

    f32x16 acc[MT];
#pragma unroll
    for (int m = 0; m < MT; ++m)
#pragma unroll
        for (int e = 0; e < 16; ++e)
            acc[m][e] = 0.0f;

    const unsigned short* bp0 = buf + lr * S + half * 8;   // batch rows 0..31
    const unsigned short* ap = W + (size_t)wave * MT * K16 * 512 + lane * 8;

    // prologue: fill the 2-slot ring (K16 >= 4 in all instantiations)
    bf16x8 aPf[2][MT];
#pragma unroll
    for (int d = 0; d < 2; ++d)
#pragma unroll
        for (int m = 0; m < MT; ++m)
            aPf[d][m] = *(const bf16x8*)(ap + ((size_t)m * K16 + d) * 512);

    // full iterations: consume k=kb+u from slot u, reload slot u with k+2
#pragma unroll 1
    for (int kb = 0; kb + 3 < K16; kb += 2) {
#pragma unroll
        for (int u = 0; u < 2; ++u) {
            int k = kb + u;
            bf16x8 b0 = *(const bf16x8*)(bp0 + k * 16);
            bf16x8 a[MT];
#pragma unroll
            for (int m = 0; m < MT; ++m) a[m] = aPf[u][m];
#pragma unroll
            for (int m = 0; m < MT; ++m)
                aPf[u][m] =
                    *(const bf16x8*)(ap + ((size_t)m * K16 + k + 2) * 512);
#pragma unroll
            for (int m = 0; m < MT; ++m)
                acc[m] = MFMA(a[m], b0, acc[m], 0, 0, 0);
        }
    }
    // tail: last 2 k's, no reload (ring slots hold exactly these)
#pragma unroll
    for (int u = 0; u < 2; ++u) {
        int k = K16 - 2 + u;
        bf16x8 b0 = *(const bf16x8*)(bp0 + k * 16);
#pragma unroll
        for (int m = 0; m < MT; ++m)
            acc[m] = MFMA(aPf[u][m], b0, acc[m], 0, 0, 0);
    }

    // ---- pre-barrier: bias + sigmoid in registers (no LDS touched) ----
#pragma unroll
    for (int m = 0; m < MT; ++m) {
        int mt = wave * MT + m;
#pragma unroll
        for (int g = 0; g < 4; ++g) {
            int f0 = mt * 32 + g * 8 + half * 4;
            float4 bv = *(const float4*)(bias + f0);
            acc[m][g * 4 + 0] = sigmoidf(acc[m][g * 4 + 0] + bv.x);
            acc[m][g * 4 + 1] = sigmoidf(acc[m][g * 4 + 1] + bv.y);
            acc[m][g * 4 + 2] = sigmoidf(acc[m][g * 4 + 2] + bv.z);
            acc[m][g * 4 + 3] = sigmoidf(acc[m][g * 4 + 3] + bv.w);
        }
    }

    __syncthreads();   // all waves' B-reads done before in-place overwrite

    // ---- post-barrier: pack + write only ----
#pragma unroll
    for (int m = 0; m < MT; ++m) {
        int mt = wave * MT + m;
#pragma unroll
        for (int g = 0; g < 4; ++g) {
            int f0 = mt * 32 + g * 8 + half * 4;   // 4 consecutive features
            int r = lr;
            if constexpr (TO_LDS) {
                bf16x4 h = {(__bf16)acc[m][g * 4 + 0],
                            (__bf16)acc[m][g * 4 + 1],
                            (__bf16)acc[m][g * 4 + 2],
                            (__bf16)acc[m][g * 4 + 3]};
                *(bf16x4*)(buf + r * S + f0) = h;      // packed b64
            } else {
                float* fb = (float*)buf;
                *(float4*)(fb + r * SF + f0) =
                    make_float4(acc[m][g * 4 + 0], acc[m][g * 4 + 1],
                                acc[m][g * 4 + 2], acc[m][g * 4 + 3]);
            }
        }
    }
}

__global__ void __launch_bounds__(256, 4)   // 128-reg class, 4 blocks/CU (133 KB LDS)
mlp_fused(MlpParams p, float* __restrict__ out) {
    extern __shared__ unsigned short buf[];

    // ---- type-INTERLEAVED block mapping (r7-proven) ----
    // 12-slot pattern, exact 5:4:3 type ratio (BM=32: 3125/2500/1875 blocks,
    // grid 7500 = 625*12 exactly). Co-resident blocks are mostly different
    // types -> phase-diverse CUs.
    // P   = [0,1,2,0,1,0,2,1,0,2,1,0]  (2-bit packed)
    // rank= [0,0,0,1,1,2,1,2,3,2,3,4]  (3-bit packed); count[t] = 5-t
    int g = blockIdx.x;
    int rep = g / 12;
    int pos = g - rep * 12;
    int t = (int)((0x186124u >> (pos * 2)) & 3u);
    int rk = (int)((0x8D3451200ULL >> (pos * 3)) & 7u);
    int blk = rep * (5 - t) + rk;

    int dIn = p.dIn[t];
    int Nt = p.Nt[t];
    int row0 = blk * BM;
    const float* X = p.X[t];
    const unsigned short* W1 = p.Wp[t];
    const unsigned short* W2 = W1 + dIn * 512;
    const unsigned short* W3 = W2 + 512 * 512;

    int tid = threadIdx.x;
    int wave = tid >> 6;
    int lane = tid & 63;

    // ---- stage X (fp32 global -> bf16 LDS rows [batch][feat]) ----
    int d4 = dIn >> 2;               // float4 per row (16/32/64)
    int s4 = 31 - __clz(d4);
    int nf4 = BM * d4;
    for (int i = tid; i < nf4; i += 256) {
        int r = i >> s4;
        int c4 = i & (d4 - 1);
        int grow = row0 + r;
        float4 v = make_float4(0.f, 0.f, 0.f, 0.f);
        if (grow < Nt) v = ((const float4*)X)[(size_t)grow * d4 + c4];
        ushort4 u;
        u.x = __builtin_bit_cast(unsigned short, (__bf16)v.x);
        u.y = __builtin_bit_cast(unsigned short, (__bf16)v.y);
        u.z = __builtin_bit_cast(unsigned short, (__bf16)v.z);
        u.w = __builtin_bit_cast(unsigned short, (__bf16)v.w);
        *(ushort4*)(buf + r * S + c4 * 4) = u;
    }
    __syncthreads();

    // L1: X -> H1 in place (K16 = dIn/16, compile-time per type); MT=4
    if (t == 0)      layerP<4,  4, true>(buf, W1, p.B1[0], wave, lane);
    else if (t == 1) layerP<8,  4, true>(buf, W1, p.B1[1], wave, lane);
    else             layerP<16, 4, true>(buf, W1, p.B1[2], wave, lane);
    __syncthreads();
    // L2: H1 -> H2 in place   (512 feats, MT=4)
    layerP<32, 4, true>(buf, W2, p.B2[t], wave, lane);
    __syncthreads();
    // L3: H2 -> f32 staging   (256 feats, MT=2)
    layerP<32, 2, false>(buf, W3, p.B3[t], wave, lane);
    __syncthreads();

    // ---- coalesced output store: 32 rows x 256 f32, full 1KB rows ----
    const float* fb = (const float*)buf;
    float* gOut = out + (size_t)(p.rowOff[t] + row0) * 256;
    for (int i = tid; i < BM * 64; i += 256) {   // 2048 float4
        int r = i >> 6;
        int c4 = i & 63;
        if (row0 + r < Nt)
            *(float4*)(gOut + r * 256 + c4 * 4) =
                *(const float4*)(fb + r * SF + c4 * 4);
    }
}

// ---------------- launch ----------------
extern "C" void kernel_launch(void* const* d_in, const int* in_sizes, int n_in,
                              void* d_out, int out_size, void* d_ws, size_t ws_size,
                              hipStream_t stream) {
    const int IN0[3] = {64, 128, 256};
    const int CNT[3] = {100000, 80000, 60000};

    // ---- prepack weights into ws (bf16, A-fragment-ordered for 32x32x16) ----
    PrepParams pp;
    int blocks = 0, ubase = 0;
    for (int t = 0; t < 3; ++t) {
        int Ks[3] = {IN0[t], 512, 512};
        int Ns[3] = {512, 512, 256};
        for (int l = 0; l < 3; ++l) {
            int w = t * 3 + l;
            pp.src[w] = (const float*)d_in[4 + t * 6 + l * 2];
            pp.Kt[w] = Ks[l] >> 5;
            pp.Mg[w] = Ns[l] >> 7;
            pp.N[w] = Ns[l];
            pp.unitBase[w] = ubase;
            blocks += pp.Kt[w] * pp.Mg[w];
            pp.blkEnd[w] = blocks;
            ubase += (Ks[l] * Ns[l]) >> 3;
        }
    }
    prep_weights<<<dim3(blocks), dim3(256), 0, stream>>>(pp, (uint4*)d_ws);

    // ---- fused MLP ----
    MlpParams mp;
    int woff = 0, roff = 0, boff = 0;
    for (int t = 0; t < 3; ++t) {
        mp.X[t] = (const float*)d_in[t];
        mp.Wp[t] = (const unsigned short*)d_ws + woff;
        mp.B1[t] = (const float*)d_in[4 + t * 6 + 1];
        mp.B2[t] = (const float*)d_in[4 + t * 6 + 3];
        mp.B3[t] = (const float*)d_in[4 + t * 6 + 5];
        mp.dIn[t] = IN0[t];
        mp.Nt[t] = CNT[t];
        mp.rowOff[t] = roff;
        woff += IN0[t] * 512 + 512 * 512 + 512 * 256;
        roff += CNT[t];
        boff += (CNT[t] + BM - 1) / BM;
    }
    size_t lds = (size_t)BM * S * sizeof(unsigned short);   // 33,280 B
    mlp_fused<<<dim3(boff), dim3(256), lds, stream>>>(mp, (float*)d_out);
}

// Round 9
// 642.465 us; speedup vs baseline: 1.0131x; 1.0131x over previous
//
#include <hip/hip_runtime.h>
#include <hip/hip_bf16.h>

typedef __bf16 bf16x8 __attribute__((ext_vector_type(8)));
typedef __bf16 bf16x4 __attribute__((ext_vector_type(4)));
typedef float  f32x16 __attribute__((ext_vector_type(16)));

#define MFMA __builtin_amdgcn_mfma_f32_32x32x16_bf16
#define BM 64            // batch rows per block (2 batch-tiles of 32)
#define S  520           // bf16 elems per LDS activation row (512 + 8)
#define SF 260           // f32 elems per LDS row for out staging (same 1040 B)

// ---------------- weight prepack (identical to round-0, verified) ----------
// A-operand = W^T for v_mfma_f32_32x32x16_bf16.
// A[m][k]: m = lane&31 (out-feature), k = (lane>>5)*8 + j.
// Packed unit u = unitBase[w] + ((mt*Kc + kc)*64 + lane), Kc = K/16; 8 bf16:
//   elem j = W[kc*16 + (lane>>5)*8 + j][mt*32 + (lane&31)]
struct PrepParams {
    const float* src[9];
    int Kt[9];       // K/32
    int Mg[9];       // N/128 (col groups)
    int N[9];
    int blkEnd[9];
    int unitBase[9];
};

__global__ void __launch_bounds__(256)
prep_weights(PrepParams p, uint4* __restrict__ dst) {
    __shared__ float tile[32][128];
    int b = blockIdx.x;
    int w = 0;
    while (b >= p.blkEnd[w]) ++w;
    int local = b - ((w == 0) ? 0 : p.blkEnd[w - 1]);
    int mgc = p.Mg[w];
    int kt = local / mgc;
    int mg = local - kt * mgc;
    const float* src = p.src[w];
    int N = p.N[w];
    int Kc = p.Kt[w] * 2;
    int t = threadIdx.x;

    int row0 = kt * 32, col0 = mg * 128;
#pragma unroll
    for (int i = 0; i < 4; ++i) {
        int e4 = t + i * 256;            // 1024 float4 in 32x128 tile
        int r = e4 >> 5;
        int c4 = e4 & 31;
        float4 v = *(const float4*)&src[(size_t)(row0 + r) * N + col0 + c4 * 4];
        *(float4*)&tile[r][c4 * 4] = v;
    }
    __syncthreads();

#pragma unroll
    for (int rep = 0; rep < 2; ++rep) {
        int ul = t + rep * 256;          // 512 units per block
        int lane = ul & 63;
        int kcl = (ul >> 6) & 1;
        int mtl = ul >> 7;               // 0..3
        int gUnit = p.unitBase[w] +
                    ((mg * 4 + mtl) * Kc + (kt * 2 + kcl)) * 64 + lane;
        int lr = kcl * 16 + ((lane >> 5) << 3);
        int lc = mtl * 32 + (lane & 31);
        alignas(16) unsigned short u8[8];
#pragma unroll
        for (int j = 0; j < 8; ++j)
            u8[j] = __builtin_bit_cast(unsigned short, (__bf16)tile[lr + j][lc]);
        dst[gUnit] = *(const uint4*)u8;
    }
}

// ---------------- fused MLP ----------------
struct MlpParams {
    const float* X[3];
    const unsigned short* Wp[3];
    const float* B1[3];
    const float* B2[3];
    const float* B3[3];
    int dIn[3];
    int Nt[3];
    int rowOff[3];
};

__device__ __forceinline__ float sigmoidf(float z) {
    return __builtin_amdgcn_rcpf(
        1.0f + __builtin_amdgcn_exp2f(-1.442695040888963f * z));
}

// r7 geometry (BM=64, 8 waves) + r8 wave shape: wave = (bt = wave>>2,
// wg = wave&3) owning MT mtiles x ONE batch-tile. Per k: 1 LDS b-read
// (was 2) + MT a-reloads -> block LDS traffic per K-step halves (16->8
// reads); the duplicated A-loads (bt=0/1 waves read same units) move the
// cost to depth-2-prefetched L2 traffic (~17 TB/s, r8-verified fine).
// Spill-safe budget (r8-verified): acc MT*16 <= 64 AGPR + ring 2*MT*4 <= 32
// + b 4 + addr ~20 <= 128-class. Early sigmoid (r7-proven).
template <int K16, int MT, bool TO_LDS>
__device__ __forceinline__ void layerP(
    unsigned short* __restrict__ buf,
    const unsigned short* __restrict__ W,
    const float* __restrict__ bias,
    int wg, int bt, int lane)
{
    const int half = lane >> 5;
    const int lr = lane & 31;

    f32x16 acc[MT];
#pragma unroll
    for (int m = 0; m < MT; ++m)
#pragma unroll
        for (int e = 0; e < 16; ++e)
            acc[m][e] = 0.0f;

    const unsigned short* bp = buf + (bt * 32 + lr) * S + half * 8;
    const unsigned short* ap = W + (size_t)wg * MT * K16 * 512 + lane * 8;

    // prologue: fill the 2-slot ring (K16 >= 4 in all instantiations)
    bf16x8 aPf[2][MT];
#pragma unroll
    for (int d = 0; d < 2; ++d)
#pragma unroll
        for (int m = 0; m < MT; ++m)
            aPf[d][m] = *(const bf16x8*)(ap + ((size_t)m * K16 + d) * 512);

    // full iterations: consume k=kb+u from slot u, reload slot u with k+2
#pragma unroll 1
    for (int kb = 0; kb + 3 < K16; kb += 2) {
#pragma unroll
        for (int u = 0; u < 2; ++u) {
            int k = kb + u;
            bf16x8 b0 = *(const bf16x8*)(bp + k * 16);
            bf16x8 a[MT];
#pragma unroll
            for (int m = 0; m < MT; ++m) a[m] = aPf[u][m];
#pragma unroll
            for (int m = 0; m < MT; ++m)
                aPf[u][m] =
                    *(const bf16x8*)(ap + ((size_t)m * K16 + k + 2) * 512);
#pragma unroll
            for (int m = 0; m < MT; ++m)
                acc[m] = MFMA(a[m], b0, acc[m], 0, 0, 0);
        }
    }
    // tail: last 2 k's, no reload (ring slots hold exactly these)
#pragma unroll
    for (int u = 0; u < 2; ++u) {
        int k = K16 - 2 + u;
        bf16x8 b0 = *(const bf16x8*)(bp + k * 16);
#pragma unroll
        for (int m = 0; m < MT; ++m)
            acc[m] = MFMA(aPf[u][m], b0, acc[m], 0, 0, 0);
    }

    // ---- pre-barrier: bias + sigmoid in registers (no LDS touched) ----
#pragma unroll
    for (int m = 0; m < MT; ++m) {
        int mt = wg * MT + m;
#pragma unroll
        for (int g = 0; g < 4; ++g) {
            int f0 = mt * 32 + g * 8 + half * 4;
            float4 bv = *(const float4*)(bias + f0);
            acc[m][g * 4 + 0] = sigmoidf(acc[m][g * 4 + 0] + bv.x);
            acc[m][g * 4 + 1] = sigmoidf(acc[m][g * 4 + 1] + bv.y);
            acc[m][g * 4 + 2] = sigmoidf(acc[m][g * 4 + 2] + bv.z);
            acc[m][g * 4 + 3] = sigmoidf(acc[m][g * 4 + 3] + bv.w);
        }
    }

    __syncthreads();   // all waves' B-reads done before in-place overwrite

    // ---- post-barrier: pack + write only ----
#pragma unroll
    for (int m = 0; m < MT; ++m) {
        int mt = wg * MT + m;
#pragma unroll
        for (int g = 0; g < 4; ++g) {
            int f0 = mt * 32 + g * 8 + half * 4;   // 4 consecutive features
            int r = bt * 32 + lr;
            if constexpr (TO_LDS) {
                bf16x4 h = {(__bf16)acc[m][g * 4 + 0],
                            (__bf16)acc[m][g * 4 + 1],
                            (__bf16)acc[m][g * 4 + 2],
                            (__bf16)acc[m][g * 4 + 3]};
                *(bf16x4*)(buf + r * S + f0) = h;      // packed b64
            } else {
                float* fb = (float*)buf;
                *(float4*)(fb + r * SF + f0) =
                    make_float4(acc[m][g * 4 + 0], acc[m][g * 4 + 1],
                                acc[m][g * 4 + 2], acc[m][g * 4 + 3]);
            }
        }
    }
}

__global__ void __launch_bounds__(512, 4)   // pin 128-reg class: 16 waves/CU, 2 blocks/CU
mlp_fused(MlpParams p, float* __restrict__ out) {
    extern __shared__ unsigned short buf[];

    // ---- type-INTERLEAVED block mapping (r7-proven) ----
    // P   = [0,1,2,0,1,0,2,1,0,2,1,0]  (2-bit packed)
    // rank= [0,0,0,1,1,2,1,2,3,2,3,4]  (3-bit packed); count[t] = 5-t
    int g = blockIdx.x;
    int rep = g / 12;
    int pos = g - rep * 12;
    int t = (int)((0x186124u >> (pos * 2)) & 3u);
    int rk = (int)((0x8D3451200ULL >> (pos * 3)) & 7u);
    int blk = rep * (5 - t) + rk;

    int dIn = p.dIn[t];
    int Nt = p.Nt[t];
    int row0 = blk * BM;
    const float* X = p.X[t];
    const unsigned short* W1 = p.Wp[t];
    const unsigned short* W2 = W1 + dIn * 512;
    const unsigned short* W3 = W2 + 512 * 512;

    int tid = threadIdx.x;
    int wave = tid >> 6;
    int lane = tid & 63;
    int wg = wave & 3;          // mtile group
    int bt = wave >> 2;         // batch-tile (0: rows 0..31, 1: rows 32..63)

    // ---- stage X (fp32 global -> bf16 LDS rows [batch][feat]) ----
    int d4 = dIn >> 2;               // float4 per row (16/32/64)
    int s4 = 31 - __clz(d4);
    int nf4 = BM * d4;
    for (int i = tid; i < nf4; i += 512) {
        int r = i >> s4;
        int c4 = i & (d4 - 1);
        int grow = row0 + r;
        float4 v = make_float4(0.f, 0.f, 0.f, 0.f);
        if (grow < Nt) v = ((const float4*)X)[(size_t)grow * d4 + c4];
        ushort4 u;
        u.x = __builtin_bit_cast(unsigned short, (__bf16)v.x);
        u.y = __builtin_bit_cast(unsigned short, (__bf16)v.y);
        u.z = __builtin_bit_cast(unsigned short, (__bf16)v.z);
        u.w = __builtin_bit_cast(unsigned short, (__bf16)v.w);
        *(ushort4*)(buf + r * S + c4 * 4) = u;
    }
    __syncthreads();

    // L1: X -> H1 in place (K16 = dIn/16, compile-time per type); MT=4
    if (t == 0)      layerP<4,  4, true>(buf, W1, p.B1[0], wg, bt, lane);
    else if (t == 1) layerP<8,  4, true>(buf, W1, p.B1[1], wg, bt, lane);
    else             layerP<16, 4, true>(buf, W1, p.B1[2], wg, bt, lane);
    __syncthreads();
    // L2: H1 -> H2 in place   (512 feats, MT=4)
    layerP<32, 4, true>(buf, W2, p.B2[t], wg, bt, lane);
    __syncthreads();
    // L3: H2 -> f32 staging   (256 feats, MT=2)
    layerP<32, 2, false>(buf, W3, p.B3[t], wg, bt, lane);
    __syncthreads();

    // ---- coalesced output store: 64 rows x 256 f32, full 1KB rows ----
    const float* fb = (const float*)buf;
    float* gOut = out + (size_t)(p.rowOff[t] + row0) * 256;
    for (int i = tid; i < BM * 64; i += 512) {   // 4096 float4
        int r = i >> 6;
        int c4 = i & 63;
        if (row0 + r < Nt)
            *(float4*)(gOut + r * 256 + c4 * 4) =
                *(const float4*)(fb + r * SF + c4 * 4);
    }
}

// ---------------- launch ----------------
extern "C" void kernel_launch(void* const* d_in, const int* in_sizes, int n_in,
                              void* d_out, int out_size, void* d_ws, size_t ws_size,
                              hipStream_t stream) {
    const int IN0[3] = {64, 128, 256};
    const int CNT[3] = {100000, 80000, 60000};

    // ---- prepack weights into ws (bf16, A-fragment-ordered for 32x32x16) ----
    PrepParams pp;
    int blocks = 0, ubase = 0;
    for (int t = 0; t < 3; ++t) {
        int Ks[3] = {IN0[t], 512, 512};
        int Ns[3] = {512, 512, 256};
        for (int l = 0; l < 3; ++l) {
            int w = t * 3 + l;
            pp.src[w] = (const float*)d_in[4 + t * 6 + l * 2];
            pp.Kt[w] = Ks[l] >> 5;
            pp.Mg[w] = Ns[l] >> 7;
            pp.N[w] = Ns[l];
            pp.unitBase[w] = ubase;
            blocks += pp.Kt[w] * pp.Mg[w];
            pp.blkEnd[w] = blocks;
            ubase += (Ks[l] * Ns[l]) >> 3;
        }
    }
    prep_weights<<<dim3(blocks), dim3(256), 0, stream>>>(pp, (uint4*)d_ws);

    // ---- fused MLP ----
    MlpParams mp;
    int woff = 0, roff = 0, boff = 0;
    for (int t = 0; t < 3; ++t) {
        mp.X[t] = (const float*)d_in[t];
        mp.Wp[t] = (const unsigned short*)d_ws + woff;
        mp.B1[t] = (const float*)d_in[4 + t * 6 + 1];
        mp.B2[t] = (const float*)d_in[4 + t * 6 + 3];
        mp.B3[t] = (const float*)d_in[4 + t * 6 + 5];
        mp.dIn[t] = IN0[t];
        mp.Nt[t] = CNT[t];
        mp.rowOff[t] = roff;
        woff += IN0[t] * 512 + 512 * 512 + 512 * 256;
        roff += CNT[t];
        boff += (CNT[t] + BM - 1) / BM;
    }
    size_t lds = (size_t)BM * S * sizeof(unsigned short);   // 66,560 B
    mlp_fused<<<dim3(boff), dim3(512), lds, stream>>>(mp, (float*)d_out);
}

// Round 10
// 561.357 us; speedup vs baseline: 1.1595x; 1.1445x over previous
//
#include <hip/hip_runtime.h>
#include <hip/hip_bf16.h>

typedef __bf16 bf16x8 __attribute__((ext_vector_type(8)));
typedef __bf16 bf16x4 __attribute__((ext_vector_type(4)));
typedef float  f32x16 __attribute__((ext_vector_type(16)));

#define MFMA __builtin_amdgcn_mfma_f32_32x32x16_bf16
#define BM 64            // batch rows per block (2 N-tiles of 32)
#define S  520           // bf16 elems per LDS activation row (512 + 8)
#define SF 260           // f32 elems per LDS row for out staging (same 1040 B)

// ---------------- weight prepack (identical to round-0, verified) ----------
// A-operand = W^T for v_mfma_f32_32x32x16_bf16.
// A[m][k]: m = lane&31 (out-feature), k = (lane>>5)*8 + j.
// Packed unit u = unitBase[w] + ((mt*Kc + kc)*64 + lane), Kc = K/16; 8 bf16:
//   elem j = W[kc*16 + (lane>>5)*8 + j][mt*32 + (lane&31)]
struct PrepParams {
    const float* src[9];
    int Kt[9];       // K/32
    int Mg[9];       // N/128 (col groups)
    int N[9];
    int blkEnd[9];
    int unitBase[9];
};

__global__ void __launch_bounds__(256)
prep_weights(PrepParams p, uint4* __restrict__ dst) {
    __shared__ float tile[32][128];
    int b = blockIdx.x;
    int w = 0;
    while (b >= p.blkEnd[w]) ++w;
    int local = b - ((w == 0) ? 0 : p.blkEnd[w - 1]);
    int mgc = p.Mg[w];
    int kt = local / mgc;
    int mg = local - kt * mgc;
    const float* src = p.src[w];
    int N = p.N[w];
    int Kc = p.Kt[w] * 2;
    int t = threadIdx.x;

    int row0 = kt * 32, col0 = mg * 128;
#pragma unroll
    for (int i = 0; i < 4; ++i) {
        int e4 = t + i * 256;            // 1024 float4 in 32x128 tile
        int r = e4 >> 5;
        int c4 = e4 & 31;
        float4 v = *(const float4*)&src[(size_t)(row0 + r) * N + col0 + c4 * 4];
        *(float4*)&tile[r][c4 * 4] = v;
    }
    __syncthreads();

#pragma unroll
    for (int rep = 0; rep < 2; ++rep) {
        int ul = t + rep * 256;          // 512 units per block
        int lane = ul & 63;
        int kcl = (ul >> 6) & 1;
        int mtl = ul >> 7;               // 0..3
        int gUnit = p.unitBase[w] +
                    ((mg * 4 + mtl) * Kc + (kt * 2 + kcl)) * 64 + lane;
        int lr = kcl * 16 + ((lane >> 5) << 3);
        int lc = mtl * 32 + (lane & 31);
        alignas(16) unsigned short u8[8];
#pragma unroll
        for (int j = 0; j < 8; ++j)
            u8[j] = __builtin_bit_cast(unsigned short, (__bf16)tile[lr + j][lc]);
        dst[gUnit] = *(const uint4*)u8;
    }
}

// ---------------- fused MLP ----------------
struct MlpParams {
    const float* X[3];
    const unsigned short* Wp[3];
    const float* B1[3];
    const float* B2[3];
    const float* B3[3];
    int dIn[3];
    int Nt[3];
    int rowOff[3];
};

__device__ __forceinline__ float sigmoidf(float z) {
    return __builtin_amdgcn_rcpf(
        1.0f + __builtin_amdgcn_exp2f(-1.442695040888963f * z));
}

// r7 layer (BM=64, 8 waves, wave = MT mtiles x 2 bt) with DEPTH-3 A-ring.
// Ring 3*MT*4 = 24 VGPR (+8 vs depth-2): use-distance 3 iters (~384 cyc)
// vs L2-under-load latency ~300-450. Main loop = (K16-3)/3 unroll-1 iters
// of 3 static ring positions; tail fully unrolled (literal bounds -> slot
// index k%3 constant-folds; rule-#20 safe). Spill budget: acc 64 AGPR +
// ring 24 + b 8 + copies 8 + addr ~12 -> ~56 of 64 VGPRs (128-class).
// Early sigmoid (r7-proven): bias+sigmoid pre-barrier; pack+write post.
template <int K16, int MT, bool TO_LDS>
__device__ __forceinline__ void layerP(
    unsigned short* __restrict__ buf,
    const unsigned short* __restrict__ W,
    const float* __restrict__ bias,
    int wave, int lane)
{
    const int half = lane >> 5;
    const int lr = lane & 31;

    f32x16 acc[2][MT];
#pragma unroll
    for (int n = 0; n < 2; ++n)
#pragma unroll
        for (int m = 0; m < MT; ++m)
#pragma unroll
            for (int e = 0; e < 16; ++e)
                acc[n][m][e] = 0.0f;

    const unsigned short* bp0 = buf + lr * S + half * 8;   // batch rows 0..31
    const unsigned short* bp1 = bp0 + 32 * S;              // batch rows 32..63
    const unsigned short* ap = W + (size_t)wave * MT * K16 * 512 + lane * 8;

    // prologue: fill the 3-slot ring (K16 >= 4 in all instantiations)
    bf16x8 aPf[3][MT];
#pragma unroll
    for (int d = 0; d < 3; ++d)
#pragma unroll
        for (int m = 0; m < MT; ++m)
            aPf[d][m] = *(const bf16x8*)(ap + ((size_t)m * K16 + d) * 512);

    // main: TMAIN periods of 3; consume slot u (k = 3*i+u), reload with k+3
    constexpr int TMAIN = (K16 - 3) / 3;
#pragma unroll 1
    for (int i = 0; i < TMAIN; ++i) {
        int kb = i * 3;
#pragma unroll
        for (int u = 0; u < 3; ++u) {
            int k = kb + u;
            bf16x8 b0 = *(const bf16x8*)(bp0 + k * 16);
            bf16x8 b1 = *(const bf16x8*)(bp1 + k * 16);
            bf16x8 a[MT];
#pragma unroll
            for (int m = 0; m < MT; ++m) a[m] = aPf[u][m];
#pragma unroll
            for (int m = 0; m < MT; ++m)
                aPf[u][m] =
                    *(const bf16x8*)(ap + ((size_t)m * K16 + k + 3) * 512);
#pragma unroll
            for (int m = 0; m < MT; ++m) {
                acc[0][m] = MFMA(a[m], b0, acc[0][m], 0, 0, 0);
                acc[1][m] = MFMA(a[m], b1, acc[1][m], 0, 0, 0);
            }
        }
    }
    // tail: k = 3*TMAIN .. K16-1, fully unrolled (literal bounds): slot k%3
    // constant-folds; reload only while k+3 < K16.
#pragma unroll
    for (int k = 3 * TMAIN; k < K16; ++k) {
        bf16x8 b0 = *(const bf16x8*)(bp0 + k * 16);
        bf16x8 b1 = *(const bf16x8*)(bp1 + k * 16);
        bf16x8 a[MT];
#pragma unroll
        for (int m = 0; m < MT; ++m) a[m] = aPf[k % 3][m];
        if (k + 3 < K16) {
#pragma unroll
            for (int m = 0; m < MT; ++m)
                aPf[k % 3][m] =
                    *(const bf16x8*)(ap + ((size_t)m * K16 + k + 3) * 512);
        }
#pragma unroll
        for (int m = 0; m < MT; ++m) {
            acc[0][m] = MFMA(a[m], b0, acc[0][m], 0, 0, 0);
            acc[1][m] = MFMA(a[m], b1, acc[1][m], 0, 0, 0);
        }
    }

    // ---- pre-barrier: bias + sigmoid in registers (no LDS touched) ----
#pragma unroll
    for (int m = 0; m < MT; ++m) {
        int mt = wave * MT + m;
#pragma unroll
        for (int g = 0; g < 4; ++g) {
            int f0 = mt * 32 + g * 8 + half * 4;
            float4 bv = *(const float4*)(bias + f0);
#pragma unroll
            for (int n = 0; n < 2; ++n) {
                acc[n][m][g * 4 + 0] = sigmoidf(acc[n][m][g * 4 + 0] + bv.x);
                acc[n][m][g * 4 + 1] = sigmoidf(acc[n][m][g * 4 + 1] + bv.y);
                acc[n][m][g * 4 + 2] = sigmoidf(acc[n][m][g * 4 + 2] + bv.z);
                acc[n][m][g * 4 + 3] = sigmoidf(acc[n][m][g * 4 + 3] + bv.w);
            }
        }
    }

    __syncthreads();   // all waves' B-reads done before in-place overwrite

    // ---- post-barrier: pack + write only ----
#pragma unroll
    for (int m = 0; m < MT; ++m) {
        int mt = wave * MT + m;
#pragma unroll
        for (int g = 0; g < 4; ++g) {
            int f0 = mt * 32 + g * 8 + half * 4;   // 4 consecutive features
#pragma unroll
            for (int n = 0; n < 2; ++n) {
                int r = n * 32 + lr;
                if constexpr (TO_LDS) {
                    bf16x4 h = {(__bf16)acc[n][m][g * 4 + 0],
                                (__bf16)acc[n][m][g * 4 + 1],
                                (__bf16)acc[n][m][g * 4 + 2],
                                (__bf16)acc[n][m][g * 4 + 3]};
                    *(bf16x4*)(buf + r * S + f0) = h;      // packed b64
                } else {
                    float* fb = (float*)buf;
                    *(float4*)(fb + r * SF + f0) =
                        make_float4(acc[n][m][g * 4 + 0], acc[n][m][g * 4 + 1],
                                    acc[n][m][g * 4 + 2], acc[n][m][g * 4 + 3]);
                }
            }
        }
    }
}

__global__ void __launch_bounds__(512, 4)   // pin 128-reg class: 16 waves/CU, 2 blocks/CU
mlp_fused(MlpParams p, float* __restrict__ out) {
    extern __shared__ unsigned short buf[];

    // ---- type-INTERLEAVED block mapping (r7-proven) ----
    // P   = [0,1,2,0,1,0,2,1,0,2,1,0]  (2-bit packed)
    // rank= [0,0,0,1,1,2,1,2,3,2,3,4]  (3-bit packed); count[t] = 5-t
    int g = blockIdx.x;
    int rep = g / 12;
    int pos = g - rep * 12;
    int t = (int)((0x186124u >> (pos * 2)) & 3u);
    int rk = (int)((0x8D3451200ULL >> (pos * 3)) & 7u);
    int blk = rep * (5 - t) + rk;

    int dIn = p.dIn[t];
    int Nt = p.Nt[t];
    int row0 = blk * BM;
    const float* X = p.X[t];
    const unsigned short* W1 = p.Wp[t];
    const unsigned short* W2 = W1 + dIn * 512;
    const unsigned short* W3 = W2 + 512 * 512;

    int tid = threadIdx.x;
    int wave = tid >> 6;
    int lane = tid & 63;

    // ---- stage X (fp32 global -> bf16 LDS rows [batch][feat]) ----
    int d4 = dIn >> 2;               // float4 per row (16/32/64)
    int s4 = 31 - __clz(d4);
    int nf4 = BM * d4;
    for (int i = tid; i < nf4; i += 512) {
        int r = i >> s4;
        int c4 = i & (d4 - 1);
        int grow = row0 + r;
        float4 v = make_float4(0.f, 0.f, 0.f, 0.f);
        if (grow < Nt) v = ((const float4*)X)[(size_t)grow * d4 + c4];
        ushort4 u;
        u.x = __builtin_bit_cast(unsigned short, (__bf16)v.x);
        u.y = __builtin_bit_cast(unsigned short, (__bf16)v.y);
        u.z = __builtin_bit_cast(unsigned short, (__bf16)v.z);
        u.w = __builtin_bit_cast(unsigned short, (__bf16)v.w);
        *(ushort4*)(buf + r * S + c4 * 4) = u;
    }
    __syncthreads();

    // L1: X -> H1 in place (K16 = dIn/16, compile-time per type)
    if (t == 0)      layerP<4,  2, true>(buf, W1, p.B1[0], wave, lane);
    else if (t == 1) layerP<8,  2, true>(buf, W1, p.B1[1], wave, lane);
    else             layerP<16, 2, true>(buf, W1, p.B1[2], wave, lane);
    __syncthreads();
    // L2: H1 -> H2 in place   (512 feats)
    layerP<32, 2, true>(buf, W2, p.B2[t], wave, lane);
    __syncthreads();
    // L3: H2 -> f32 staging   (256 feats, 1 mtile/wave)
    layerP<32, 1, false>(buf, W3, p.B3[t], wave, lane);
    __syncthreads();

    // ---- coalesced output store: 64 rows x 256 f32, full 1KB rows ----
    const float* fb = (const float*)buf;
    float* gOut = out + (size_t)(p.rowOff[t] + row0) * 256;
    for (int i = tid; i < BM * 64; i += 512) {   // 4096 float4
        int r = i >> 6;
        int c4 = i & 63;
        if (row0 + r < Nt)
            *(float4*)(gOut + r * 256 + c4 * 4) =
                *(const float4*)(fb + r * SF + c4 * 4);
    }
}

// ---------------- launch ----------------
extern "C" void kernel_launch(void* const* d_in, const int* in_sizes, int n_in,
                              void* d_out, int out_size, void* d_ws, size_t ws_size,
                              hipStream_t stream) {
    const int IN0[3] = {64, 128, 256};
    const int CNT[3] = {100000, 80000, 60000};

    // ---- prepack weights into ws (bf16, A-fragment-ordered for 32x32x16) ----
    PrepParams pp;
    int blocks = 0, ubase = 0;
    for (int t = 0; t < 3; ++t) {
        int Ks[3] = {IN0[t], 512, 512};
        int Ns[3] = {512, 512, 256};
        for (int l = 0; l < 3; ++l) {
            int w = t * 3 + l;
            pp.src[w] = (const float*)d_in[4 + t * 6 + l * 2];
            pp.Kt[w] = Ks[l] >> 5;
            pp.Mg[w] = Ns[l] >> 7;
            pp.N[w] = Ns[l];
            pp.unitBase[w] = ubase;
            blocks += pp.Kt[w] * pp.Mg[w];
            pp.blkEnd[w] = blocks;
            ubase += (Ks[l] * Ns[l]) >> 3;
        }
    }
    prep_weights<<<dim3(blocks), dim3(256), 0, stream>>>(pp, (uint4*)d_ws);

    // ---- fused MLP ----
    MlpParams mp;
    int woff = 0, roff = 0, boff = 0;
    for (int t = 0; t < 3; ++t) {
        mp.X[t] = (const float*)d_in[t];
        mp.Wp[t] = (const unsigned short*)d_ws + woff;
        mp.B1[t] = (const float*)d_in[4 + t * 6 + 1];
        mp.B2[t] = (const float*)d_in[4 + t * 6 + 3];
        mp.B3[t] = (const float*)d_in[4 + t * 6 + 5];
        mp.dIn[t] = IN0[t];
        mp.Nt[t] = CNT[t];
        mp.rowOff[t] = roff;
        woff += IN0[t] * 512 + 512 * 512 + 512 * 256;
        roff += CNT[t];
        boff += (CNT[t] + BM - 1) / BM;
    }
    size_t lds = (size_t)BM * S * sizeof(unsigned short);   // 66,560 B
    mlp_fused<<<dim3(boff), dim3(512), lds, stream>>>(mp, (float*)d_out);
}